// Round 5
// baseline (935.802 us; speedup 1.0000x reference)
//
#include <hip/hip_runtime.h>

#define D_    784
#define ROWS  32              // batch rows per block; 8 float4 chunks = 128 B = all 32 banks
#define NCLS  10
#define BLOCK 512             // 8 waves
#define NWAVE 8
#define NPG   13              // n = g + 64*i, guard last
#define NB    (65536 / ROWS)  // 2048 blocks

// feature n, logical row-chunk c (rows 4c..4c+3) -> dword offset.
// slot rotation (c+n)&7 keeps chunks b128-contiguous; any 8-lane group
// reading chunks 0..7 of one n covers all 32 banks exactly once.
__device__ __forceinline__ int hq(int n, int c) {
    return n * 32 + (((c + n) & 7) << 2);
}

// tanh-approx GELU (|err| vs exact erf-GELU ~5e-4)
__device__ __forceinline__ float gelu_f(float x) {
    float x2    = x * x;
    float inner = fmaf(0.044715f * x, x2, x);
    float e     = exp2f(2.3022082f * inner);          // 2*sqrt(2/pi)*log2(e)
    float r     = __builtin_amdgcn_rcpf(e + 1.0f);
    return fmaf(-x, r, x);                            // x*e/(e+1)
}

__device__ __forceinline__ void fma4(float4& a, const float4& h4, float wk) {
    a.x = fmaf(h4.x, wk, a.x);
    a.y = fmaf(h4.y, wk, a.y);
    a.z = fmaf(h4.z, wk, a.z);
    a.w = fmaf(h4.w, wk, a.w);
}

// In-place sparse layer. Thread (g = tid>>3, q = tid&7) owns rows 4q..4q+3
// (one float4) for n = g + 64*i. All LDS ops are conflict-free b128.
template <int K>
__device__ __forceinline__ void layer_fn(float* __restrict__ h,
                                         const int* __restrict__ idx,
                                         const float* __restrict__ w,
                                         const float* __restrict__ bias,
                                         int g, int q) {
    float4 acc[NPG];
#pragma unroll
    for (int i = 0; i < NPG; ++i) {
        int n = g + 64 * i;
        float4 a = make_float4(0.f, 0.f, 0.f, 0.f);
        if (n < D_) {
            float bv = bias[n];
            a.x = bv; a.y = bv; a.z = bv; a.w = bv;
            if constexpr (K == 2) {
                int2   j2 = *(const int2*)(idx + n * 2);
                float2 wv = *(const float2*)(w + n * 2);
                float4 h0 = *(const float4*)(h + hq(j2.x, q));
                float4 h1 = *(const float4*)(h + hq(j2.y, q));
                fma4(a, h0, wv.x);
                fma4(a, h1, wv.y);
            } else if constexpr (K == 4) {
                int4   j4 = *(const int4*)(idx + n * 4);
                float4 wv = *(const float4*)(w + n * 4);
                float4 h0 = *(const float4*)(h + hq(j4.x, q));
                float4 h1 = *(const float4*)(h + hq(j4.y, q));
                float4 h2 = *(const float4*)(h + hq(j4.z, q));
                float4 h3 = *(const float4*)(h + hq(j4.w, q));
                fma4(a, h0, wv.x);
                fma4(a, h1, wv.y);
                fma4(a, h2, wv.z);
                fma4(a, h3, wv.w);
            } else { // K == 8, two half-rounds to bound in-flight regs
                {
                    int4   ja = *(const int4*)(idx + n * 8);
                    float4 wa = *(const float4*)(w + n * 8);
                    float4 h0 = *(const float4*)(h + hq(ja.x, q));
                    float4 h1 = *(const float4*)(h + hq(ja.y, q));
                    float4 h2 = *(const float4*)(h + hq(ja.z, q));
                    float4 h3 = *(const float4*)(h + hq(ja.w, q));
                    fma4(a, h0, wa.x);
                    fma4(a, h1, wa.y);
                    fma4(a, h2, wa.z);
                    fma4(a, h3, wa.w);
                }
                {
                    int4   jb = *(const int4*)(idx + n * 8 + 4);
                    float4 wb = *(const float4*)(w + n * 8 + 4);
                    float4 h4 = *(const float4*)(h + hq(jb.x, q));
                    float4 h5 = *(const float4*)(h + hq(jb.y, q));
                    float4 h6 = *(const float4*)(h + hq(jb.z, q));
                    float4 h7 = *(const float4*)(h + hq(jb.w, q));
                    fma4(a, h4, wb.x);
                    fma4(a, h5, wb.y);
                    fma4(a, h6, wb.z);
                    fma4(a, h7, wb.w);
                }
            }
        }
        acc[i] = a;
    }
    __syncthreads();
#pragma unroll
    for (int i = 0; i < NPG; ++i) {
        int n = g + 64 * i;
        if (n < D_) {
            float4 gv = make_float4(gelu_f(acc[i].x), gelu_f(acc[i].y),
                                    gelu_f(acc[i].z), gelu_f(acc[i].w));
            *(float4*)(h + hq(n, q)) = gv;
        }
    }
    __syncthreads();
}

__global__ __launch_bounds__(BLOCK, 2)   // 2 waves/EU -> VGPR cap 256, no spill
void circnn_kernel(const float* __restrict__ x,
                   const int* __restrict__ idx1, const float* __restrict__ w1, const float* __restrict__ b1,
                   const int* __restrict__ idx2, const float* __restrict__ w2, const float* __restrict__ b2,
                   const int* __restrict__ idx3, const float* __restrict__ w3, const float* __restrict__ b3,
                   const float* __restrict__ fcw, const float* __restrict__ fcb,
                   float* __restrict__ out) {
    __shared__ __align__(16) float  h[D_ * 32];              // 100,352 B
    __shared__ __align__(16) float4 red4[NWAVE * 8 * NCLS];  // 10,240 B
    __shared__ float logits[ROWS * NCLS];                    // 1,280 B

    const int tid  = threadIdx.x;
    const int g    = tid >> 3;        // group 0..63 (feature subset)
    const int q    = tid & 7;         // row-chunk 0..7 (rows 4q..4q+3)
    const int row0 = blockIdx.x * ROWS;

    // ---- Stage x: 4 strided-coalesced b32 global reads -> one b128 LDS write
    const float* xb = x + (size_t)row0 * D_;
#pragma unroll
    for (int rq = 0; rq < 8; ++rq) {
        for (int n = tid; n < D_; n += BLOCK) {
            float4 v;
            v.x = xb[(rq * 4 + 0) * D_ + n];
            v.y = xb[(rq * 4 + 1) * D_ + n];
            v.z = xb[(rq * 4 + 2) * D_ + n];
            v.w = xb[(rq * 4 + 3) * D_ + n];
            *(float4*)(h + hq(n, rq)) = v;
        }
    }
    __syncthreads();

    // ---- Three sparse layers, in place ----
    layer_fn<2>(h, idx1, w1, b1, g, q);
    layer_fn<4>(h, idx2, w2, b2, g, q);
    layer_fn<8>(h, idx3, w3, b3, g, q);

    // ---- FC 784->10 ----
    float4 facc[NCLS];
#pragma unroll
    for (int c = 0; c < NCLS; ++c) facc[c] = make_float4(0.f, 0.f, 0.f, 0.f);
#pragma unroll
    for (int i = 0; i < NPG; ++i) {
        int n = g + 64 * i;
        if (n < D_) {
            float4 hv = *(const float4*)(h + hq(n, q));
#pragma unroll
            for (int c = 0; c < NCLS; ++c)
                fma4(facc[c], hv, fcw[c * D_ + n]);
        }
    }
    // reduce over g-bits inside the wave (tid bits 3,4,5)
#pragma unroll
    for (int m = 8; m <= 32; m <<= 1) {
#pragma unroll
        for (int c = 0; c < NCLS; ++c) {
            facc[c].x += __shfl_xor(facc[c].x, m, 64);
            facc[c].y += __shfl_xor(facc[c].y, m, 64);
            facc[c].z += __shfl_xor(facc[c].z, m, 64);
            facc[c].w += __shfl_xor(facc[c].w, m, 64);
        }
    }
    const int wv_  = tid >> 6;        // wave 0..7
    const int lane = tid & 63;
    if ((lane & 56) == 0) {           // one lane per (wave, q)
#pragma unroll
        for (int c = 0; c < NCLS; ++c)
            red4[(wv_ * 8 + q) * NCLS + c] = facc[c];
    }
    __syncthreads();

    // ---- combine wave partials -> logits[r][c] ----
    if (tid < ROWS * NCLS) {          // 320 threads
        int r = tid / NCLS, c = tid - r * NCLS;
        int rq = r >> 2, comp = r & 3;
        float s = fcb[c];
#pragma unroll
        for (int k = 0; k < NWAVE; ++k) {
            float4 v = red4[(k * 8 + rq) * NCLS + c];
            s += (comp == 0) ? v.x : (comp == 1) ? v.y : (comp == 2) ? v.z : v.w;
        }
        logits[tid] = s;
    }
    __syncthreads();

    // ---- softmax (redundant per-(r,c) thread), coalesced 320-float store ----
    if (tid < ROWS * NCLS) {
        int r = tid / NCLS;
        const float* lg = logits + r * NCLS;
        float m = lg[0];
#pragma unroll
        for (int c = 1; c < NCLS; ++c) m = fmaxf(m, lg[c]);
        float s = 0.f;
#pragma unroll
        for (int c = 0; c < NCLS; ++c) s += __expf(lg[c] - m);
        out[(size_t)row0 * NCLS + tid] = __expf(logits[tid] - m) / s;
    }
}

extern "C" void kernel_launch(void* const* d_in, const int* in_sizes, int n_in,
                              void* d_out, int out_size, void* d_ws, size_t ws_size,
                              hipStream_t stream) {
    const float* x    = (const float*)d_in[0];
    const int*   idx1 = (const int*)d_in[1];
    const float* w1   = (const float*)d_in[2];
    const float* b1   = (const float*)d_in[3];
    const int*   idx2 = (const int*)d_in[4];
    const float* w2   = (const float*)d_in[5];
    const float* b2   = (const float*)d_in[6];
    const int*   idx3 = (const int*)d_in[7];
    const float* w3   = (const float*)d_in[8];
    const float* b3   = (const float*)d_in[9];
    const float* fcw  = (const float*)d_in[10];
    const float* fcb  = (const float*)d_in[11];
    float* out = (float*)d_out;

    circnn_kernel<<<dim3(NB), dim3(BLOCK), 0, stream>>>(
        x, idx1, w1, b1, idx2, w2, b2, idx3, w3, b3, fcw, fcb, out);
}

// Round 7
// 437.007 us; speedup vs baseline: 2.1414x; 2.1414x over previous
//
#include <hip/hip_runtime.h>

#define D_    784
#define ROWS  8               // rows per block; feature = 2 float4 chunks (32 B)
#define NCLS  10
#define BLOCK 512             // 8 waves; 2 blocks/CU at 128 VGPR + 50 KB LDS
#define NB    (65536 / ROWS)  // 8192 blocks
#define NPG   4               // n = g + 256*i, g in 0..255

// tanh-approx GELU (|err| vs exact erf-GELU ~5e-4)
__device__ __forceinline__ float gelu_f(float x) {
    float x2    = x * x;
    float inner = fmaf(0.044715f * x, x2, x);
    float e     = exp2f(2.3022082f * inner);          // 2*sqrt(2/pi)*log2(e)
    float r     = __builtin_amdgcn_rcpf(e + 1.0f);
    return fmaf(-x, r, x);                            // x*e/(e+1)
}

__device__ __forceinline__ void fma4(float4& a, const float4& h4, float wk) {
    a.x = fmaf(h4.x, wk, a.x);
    a.y = fmaf(h4.y, wk, a.y);
    a.z = fmaf(h4.z, wk, a.z);
    a.w = fmaf(h4.w, wk, a.w);
}

template <int K>
__device__ __forceinline__ void loadIdxW(const int* __restrict__ idx,
                                         const float* __restrict__ w,
                                         int n, int* jc, float* wc) {
    if constexpr (K == 2) {
        int2   j = *(const int2*)(idx + n * 2);
        float2 v = *(const float2*)(w + n * 2);
        jc[0] = j.x; jc[1] = j.y; wc[0] = v.x; wc[1] = v.y;
    } else if constexpr (K == 4) {
        int4   j = *(const int4*)(idx + n * 4);
        float4 v = *(const float4*)(w + n * 4);
        jc[0] = j.x; jc[1] = j.y; jc[2] = j.z; jc[3] = j.w;
        wc[0] = v.x; wc[1] = v.y; wc[2] = v.z; wc[3] = v.w;
    } else {
        int4   ja = *(const int4*)(idx + n * 8);
        int4   jb = *(const int4*)(idx + n * 8 + 4);
        float4 va = *(const float4*)(w + n * 8);
        float4 vb = *(const float4*)(w + n * 8 + 4);
        jc[0] = ja.x; jc[1] = ja.y; jc[2] = ja.z; jc[3] = ja.w;
        jc[4] = jb.x; jc[5] = jb.y; jc[6] = jb.z; jc[7] = jb.w;
        wc[0] = va.x; wc[1] = va.y; wc[2] = va.z; wc[3] = va.w;
        wc[4] = vb.x; wc[5] = vb.y; wc[6] = vb.z; wc[7] = vb.w;
    }
}

// Ping-pong sparse layer: read src, write dst, ONE barrier at the end.
// Thread (g = tid>>1, q = tid&1) owns rows 4q..4q+3 (one float4) of
// features n = g + 256*i. No accumulator arrays -> no spill pressure.
template <int K>
__device__ __forceinline__ void layer_fn(const float* __restrict__ src,
                                         float* __restrict__ dst,
                                         const int* __restrict__ idx,
                                         const float* __restrict__ w,
                                         const float* __restrict__ bias,
                                         int g, int q) {
    int   jc[K];
    float wc[K];
    float bc;
    loadIdxW<K>(idx, w, g, jc, wc);       // i = 0 always valid (g < 784)
    bc = bias[g];
#pragma unroll 1
    for (int i = 0; i < NPG; ++i) {
        int n  = g + 256 * i;
        int nn = n + 256;
        int   jn[K]; float wn[K]; float bn = 0.f;
#pragma unroll
        for (int k = 0; k < K; ++k) { jn[k] = 0; wn[k] = 0.f; }
        if (nn < D_) {                    // prefetch i+1 while computing i
            loadIdxW<K>(idx, w, nn, jn, wn);
            bn = bias[nn];
        }
        if (n < D_) {
            float4 a = make_float4(bc, bc, bc, bc);
#pragma unroll
            for (int k = 0; k < K; ++k) {
                float4 hv = *(const float4*)(src + jc[k] * 8 + q * 4);
                fma4(a, hv, wc[k]);
            }
            *(float4*)(dst + n * 8 + q * 4) =
                make_float4(gelu_f(a.x), gelu_f(a.y), gelu_f(a.z), gelu_f(a.w));
        }
#pragma unroll
        for (int k = 0; k < K; ++k) { jc[k] = jn[k]; wc[k] = wn[k]; }
        bc = bn;
    }
    __syncthreads();
}

__global__ __launch_bounds__(BLOCK)
void circnn_kernel(const float* __restrict__ x,
                   const int* __restrict__ idx1, const float* __restrict__ w1, const float* __restrict__ b1,
                   const int* __restrict__ idx2, const float* __restrict__ w2, const float* __restrict__ b2,
                   const int* __restrict__ idx3, const float* __restrict__ w3, const float* __restrict__ b3,
                   const float* __restrict__ fcw, const float* __restrict__ fcb,
                   float* __restrict__ out) {
    __shared__ __align__(16) float bufA[D_ * ROWS];   // 25,088 B: x, h2; then FC partials
    __shared__ __align__(16) float bufB[D_ * ROWS];   // 25,088 B: h1, h3
    __shared__ float logits[ROWS * NCLS];             // 320 B

    const int tid  = threadIdx.x;
    const int g    = tid >> 1;        // feature group 0..255
    const int q    = tid & 1;         // row chunk (rows 4q..4q+3)
    const int row0 = blockIdx.x * ROWS;

    // ---- Stage x -> bufA: 4 strided-coalesced b32 reads -> one b128 write
    const float* xb = x + (size_t)row0 * D_;
#pragma unroll
    for (int c2 = 0; c2 < 2; ++c2) {
#pragma unroll 1
        for (int n = tid; n < D_; n += BLOCK) {
            float4 v;
            v.x = xb[(c2 * 4 + 0) * D_ + n];
            v.y = xb[(c2 * 4 + 1) * D_ + n];
            v.z = xb[(c2 * 4 + 2) * D_ + n];
            v.w = xb[(c2 * 4 + 3) * D_ + n];
            *(float4*)(bufA + n * 8 + c2 * 4) = v;
        }
    }
    __syncthreads();

    // ---- Three sparse layers, ping-pong: A->B->A->B
    layer_fn<2>(bufA, bufB, idx1, w1, b1, g, q);
    layer_fn<4>(bufB, bufA, idx2, w2, b2, g, q);
    layer_fn<8>(bufA, bufB, idx3, w3, b3, g, q);

    // ---- FC phase A: 128 threads, partials into bufA (free). No shuffles.
    float4* part4 = (float4*)bufA;    // layout [(jj*2+q)*NCLS + c], 20,480 B
    if (tid < 128) {
        const int jj = tid >> 1;      // 0..63
        const int qq = tid & 1;
        float4 facc[NCLS];
#pragma unroll
        for (int c = 0; c < NCLS; ++c) facc[c] = make_float4(0.f, 0.f, 0.f, 0.f);
#pragma unroll 1
        for (int i = 0; i < 13; ++i) {
            int n = jj + 64 * i;
            if (n < D_) {
                float4 hv = *(const float4*)(bufB + n * 8 + qq * 4);
#pragma unroll
                for (int c = 0; c < NCLS; ++c)
                    fma4(facc[c], hv, fcw[c * D_ + n]);
            }
        }
#pragma unroll
        for (int c = 0; c < NCLS; ++c)
            part4[(jj * 2 + qq) * NCLS + c] = facc[c];
    }
    __syncthreads();

    // ---- FC phase B: 80 threads (r, c) sum 64 partials -> logits
    if (tid < ROWS * NCLS) {
        int r = tid / NCLS, c = tid - r * NCLS;
        int qq = r >> 2, comp = r & 3;
        const float* pf = (const float*)part4;
        float s = fcb[c];
#pragma unroll 4
        for (int jj = 0; jj < 64; ++jj)
            s += pf[((jj * 2 + qq) * NCLS + c) * 4 + comp];
        logits[tid] = s;
    }
    __syncthreads();

    // ---- softmax (redundant per-(r,c) thread), coalesced 80-float store
    if (tid < ROWS * NCLS) {
        int r = tid / NCLS;
        const float* lg = logits + r * NCLS;
        float m = lg[0];
#pragma unroll
        for (int c = 1; c < NCLS; ++c) m = fmaxf(m, lg[c]);
        float s = 0.f;
#pragma unroll
        for (int c = 0; c < NCLS; ++c) s += __expf(lg[c] - m);
        out[(size_t)row0 * NCLS + tid] = __expf(logits[tid] - m) / s;
    }
}

extern "C" void kernel_launch(void* const* d_in, const int* in_sizes, int n_in,
                              void* d_out, int out_size, void* d_ws, size_t ws_size,
                              hipStream_t stream) {
    const float* x    = (const float*)d_in[0];
    const int*   idx1 = (const int*)d_in[1];
    const float* w1   = (const float*)d_in[2];
    const float* b1   = (const float*)d_in[3];
    const int*   idx2 = (const int*)d_in[4];
    const float* w2   = (const float*)d_in[5];
    const float* b2   = (const float*)d_in[6];
    const int*   idx3 = (const int*)d_in[7];
    const float* w3   = (const float*)d_in[8];
    const float* b3   = (const float*)d_in[9];
    const float* fcw  = (const float*)d_in[10];
    const float* fcb  = (const float*)d_in[11];
    float* out = (float*)d_out;

    circnn_kernel<<<dim3(NB), dim3(BLOCK), 0, stream>>>(
        x, idx1, w1, b1, idx2, w2, b2, idx3, w3, b3, fcw, fcb, out);
}